// Round 2
// baseline (548.782 us; speedup 1.0000x reference)
//
#include <hip/hip_runtime.h>
#include <hip/hip_bf16.h>

#define D_OUT 64
#define K_DIM 512

using short8  = __attribute__((ext_vector_type(8))) short;
using floatx4 = __attribute__((ext_vector_type(4))) float;

__device__ inline unsigned short f32_to_bf16(float f) {
    unsigned int u = __float_as_uint(f);
    u += 0x7FFFu + ((u >> 16) & 1u);   // round-to-nearest-even
    return (unsigned short)(u >> 16);
}

__device__ inline float bf16lo_f32(unsigned int g) {   // low ushort -> f32
    return __uint_as_float(g << 16);
}
__device__ inline float bf16hi_f32(unsigned int g) {   // high ushort -> f32
    return __uint_as_float(g & 0xFFFF0000u);
}

// ---------------------------------------------------------------------------
// Wt[n][k] = bf16(W[k][n]) : 64 x 512 bf16 (64 KB, L2-resident)
__global__ void wt_kernel(const float* __restrict__ W, unsigned short* __restrict__ wt) {
    int i = blockIdx.x * blockDim.x + threadIdx.x;
    if (i < D_OUT * K_DIM) {
        int n = i >> 9;
        int k = i & 511;
        wt[i] = f32_to_bf16(W[k * D_OUT + n]);
    }
}

// ---------------------------------------------------------------------------
// gemm: wave = 16 rows x 64 cols; batch-issued A loads; H stored bf16.
__global__ __launch_bounds__(256) void gemm_kernel(
    const float* __restrict__ A, const unsigned short* __restrict__ wt,
    unsigned short* __restrict__ H, int n) {
    const int tid  = threadIdx.x;
    const int wv   = tid >> 6;
    const int lane = tid & 63;
    const int ln   = lane & 15;
    const int quad = lane >> 4;
    const int row0 = blockIdx.x * 64 + wv * 16;

    int arow = row0 + ln;
    if (arow >= n) arow = n - 1;          // clamp (stores guarded)
    const float* Arow = A + (size_t)arow * K_DIM;
    const unsigned short* wb = wt + (size_t)ln * K_DIM;

    floatx4 acc0 = {0.f, 0.f, 0.f, 0.f};
    floatx4 acc1 = {0.f, 0.f, 0.f, 0.f};
    floatx4 acc2 = {0.f, 0.f, 0.f, 0.f};
    floatx4 acc3 = {0.f, 0.f, 0.f, 0.f};

    for (int h0 = 0; h0 < K_DIM; h0 += 128) {
        float4 t[8];
#pragma unroll
        for (int s = 0; s < 4; s++) {
            t[2 * s]     = *reinterpret_cast<const float4*>(Arow + h0 + s * 32 + quad * 8);
            t[2 * s + 1] = *reinterpret_cast<const float4*>(Arow + h0 + s * 32 + quad * 8 + 4);
        }
        short8 ab[4];
#pragma unroll
        for (int s = 0; s < 4; s++) {
            float4 a0 = t[2 * s], a1 = t[2 * s + 1];
            short8 af;
            af[0] = (short)f32_to_bf16(a0.x);
            af[1] = (short)f32_to_bf16(a0.y);
            af[2] = (short)f32_to_bf16(a0.z);
            af[3] = (short)f32_to_bf16(a0.w);
            af[4] = (short)f32_to_bf16(a1.x);
            af[5] = (short)f32_to_bf16(a1.y);
            af[6] = (short)f32_to_bf16(a1.z);
            af[7] = (short)f32_to_bf16(a1.w);
            ab[s] = af;
        }
#pragma unroll
        for (int s = 0; s < 4; s++) {
            const int ko = h0 + s * 32 + quad * 8;
            short8 b0 = *reinterpret_cast<const short8*>(wb + ko);
            short8 b1 = *reinterpret_cast<const short8*>(wb + 16 * K_DIM + ko);
            short8 b2 = *reinterpret_cast<const short8*>(wb + 32 * K_DIM + ko);
            short8 b3 = *reinterpret_cast<const short8*>(wb + 48 * K_DIM + ko);
            acc0 = __builtin_amdgcn_mfma_f32_16x16x32_bf16(ab[s], b0, acc0, 0, 0, 0);
            acc1 = __builtin_amdgcn_mfma_f32_16x16x32_bf16(ab[s], b1, acc1, 0, 0, 0);
            acc2 = __builtin_amdgcn_mfma_f32_16x16x32_bf16(ab[s], b2, acc2, 0, 0, 0);
            acc3 = __builtin_amdgcn_mfma_f32_16x16x32_bf16(ab[s], b3, acc3, 0, 0, 0);
        }
    }

    // C/D layout: col = lane&15, row = quad*4 + reg  [m89]
#pragma unroll
    for (int r = 0; r < 4; r++) {
        int gr = row0 + quad * 4 + r;
        if (gr < n) {
            unsigned short* Hr = H + (size_t)gr * D_OUT;
            Hr[ln]      = f32_to_bf16(acc0[r]);
            Hr[16 + ln] = f32_to_bf16(acc1[r]);
            Hr[32 + ln] = f32_to_bf16(acc2[r]);
            Hr[48 + ln] = f32_to_bf16(acc3[r]);
        }
    }
}

// ---------------------------------------------------------------------------
// zero the per-row counters
__global__ __launch_bounds__(256) void zero_kernel(int* __restrict__ p, int n) {
    int i = blockIdx.x * 256 + threadIdx.x;
    if (i < n) p[i] = 0;
}

// ---------------------------------------------------------------------------
// P1: per-ROW histogram via L2 atomics (avg 16 increments per counter).
__global__ __launch_bounds__(256) void count_kernel(
    const int* __restrict__ rows, int* __restrict__ counts, int E) {
    int i = blockIdx.x * 256 + threadIdx.x;
    const int stride = gridDim.x * 256;
    for (; i < E; i += stride) atomicAdd(&counts[rows[i]], 1);
}

// ---------------------------------------------------------------------------
// 3-phase scan over n = N row counts (1024 elements / block)
__global__ __launch_bounds__(256) void scan1_kernel(
    const int* __restrict__ counts, int* __restrict__ bsum, int n) {
    __shared__ int wsh[4];
    const int tid = threadIdx.x, lane = tid & 63, wid = tid >> 6;
    int i0 = blockIdx.x * 1024 + tid * 4;
    int s = 0;
#pragma unroll
    for (int j = 0; j < 4; j++) {
        int ix = i0 + j;
        s += (ix < n) ? counts[ix] : 0;
    }
#pragma unroll
    for (int d = 32; d; d >>= 1) s += __shfl_xor(s, d, 64);
    if (lane == 0) wsh[wid] = s;
    __syncthreads();
    if (tid == 0) bsum[blockIdx.x] = wsh[0] + wsh[1] + wsh[2] + wsh[3];
}

__global__ __launch_bounds__(1024) void scan2_kernel(
    const int* __restrict__ bsum, int* __restrict__ bbase,
    int* __restrict__ scanned, int nblk, int L, int E) {
    __shared__ int wsum[16];
    const int tid = threadIdx.x, lane = tid & 63, wid = tid >> 6;
    int v = (tid < nblk) ? bsum[tid] : 0;
    int x = v;
#pragma unroll
    for (int d = 1; d < 64; d <<= 1) {
        int y = __shfl_up(x, d, 64);
        if (lane >= d) x += y;
    }
    if (lane == 63) wsum[wid] = x;
    __syncthreads();
    if (tid < 16) {
        int w = wsum[tid];
        int xx = w;
#pragma unroll
        for (int d = 1; d < 16; d <<= 1) {
            int y = __shfl_up(xx, d, 64);
            if (tid >= d) xx += y;
        }
        wsum[tid] = xx - w;
    }
    __syncthreads();
    if (tid < nblk) bbase[tid] = wsum[wid] + (x - v);
    if (tid == 0) scanned[L] = E;
}

// writes exclusive scan into BOTH scanned[] (kept intact for agg) and
// cursor[] (consumed by partition's atomicAdd).
__global__ __launch_bounds__(256) void scan3_kernel(
    const int* __restrict__ counts, const int* __restrict__ bbase,
    int* __restrict__ scanned, int* __restrict__ cursor, int n) {
    __shared__ int wsum[4];
    const int tid = threadIdx.x, lane = tid & 63, wid = tid >> 6;
    const int i0 = blockIdx.x * 1024 + tid * 4;
    int v[4];
#pragma unroll
    for (int j = 0; j < 4; j++) {
        int ix = i0 + j;
        v[j] = (ix < n) ? counts[ix] : 0;
    }
#pragma unroll
    for (int j = 1; j < 4; j++) v[j] += v[j - 1];
    int t = v[3];
    int x = t;
#pragma unroll
    for (int d = 1; d < 64; d <<= 1) {
        int y = __shfl_up(x, d, 64);
        if (lane >= d) x += y;
    }
    if (lane == 63) wsum[wid] = x;
    __syncthreads();
    if (tid == 0) {
        int a = 0;
#pragma unroll
        for (int w = 0; w < 4; w++) { int tmp = wsum[w]; wsum[w] = a; a += tmp; }
    }
    __syncthreads();
    int excl = bbase[blockIdx.x] + wsum[wid] + (x - t);
#pragma unroll
    for (int j = 0; j < 4; j++) {
        int ix = i0 + j;
        if (ix < n) {
            int e = excl + ((j == 0) ? 0 : v[j - 1]);
            scanned[ix] = e;
            cursor[ix]  = e;
        }
    }
}

// ---------------------------------------------------------------------------
// P3: scatter edges directly into per-row segments: keys[p] = (col, val).
__global__ __launch_bounds__(256) void partition_kernel(
    const int* __restrict__ rows, const int* __restrict__ cols,
    const float* __restrict__ vals, int* __restrict__ cursor,
    int2* __restrict__ keys, int E) {
    int i = blockIdx.x * 256 + threadIdx.x;
    const int stride = gridDim.x * 256;
    for (; i < E; i += stride) {
        int r = rows[i];
        int p = atomicAdd(&cursor[r], 1);
        keys[p] = make_int2(cols[i], __float_as_int(vals[i]));
    }
}

// ---------------------------------------------------------------------------
// P4: pure gather-aggregate. Wave per row (grid-stride). No LDS, no barriers.
// h is bf16: a wave gathers FOUR edges per load (16 lanes/edge, uint2 = 4
// bf16 cols/lane; 128 B = one cache line per edge).
__global__ __launch_bounds__(256) void agg_kernel(
    const unsigned short* __restrict__ h, const int2* __restrict__ keys,
    const int* __restrict__ scanned, float* __restrict__ out, int N) {
    const int lane = threadIdx.x & 63;
    const int q    = lane >> 4;          // 0..3  : edge slot within wave
    const int li   = lane & 15;          // 0..15 : 4 cols per lane
    int gw = (blockIdx.x * blockDim.x + threadIdx.x) >> 6;   // global wave id
    const int nw = (gridDim.x * blockDim.x) >> 6;

    for (int r = gw; r < N; r += nw) {
        const int s = scanned[r];
        const int e = scanned[r + 1];
        float4 acc = {0.f, 0.f, 0.f, 0.f};
        int j = s;
        for (; j + 8 <= e; j += 8) {
            int2 kA = keys[j + q];
            int2 kB = keys[j + 4 + q];
            const uint2 gA = *reinterpret_cast<const uint2*>(
                h + (size_t)kA.x * D_OUT + li * 4);
            const uint2 gB = *reinterpret_cast<const uint2*>(
                h + (size_t)kB.x * D_OUT + li * 4);
            float vA = __int_as_float(kA.y);
            float vB = __int_as_float(kB.y);
            acc.x += vA * bf16lo_f32(gA.x);
            acc.y += vA * bf16hi_f32(gA.x);
            acc.z += vA * bf16lo_f32(gA.y);
            acc.w += vA * bf16hi_f32(gA.y);
            acc.x += vB * bf16lo_f32(gB.x);
            acc.y += vB * bf16hi_f32(gB.x);
            acc.z += vB * bf16lo_f32(gB.y);
            acc.w += vB * bf16hi_f32(gB.y);
        }
        for (; j < e; j += 4) {
            bool on = (j + q) < e;
            int2 kv = keys[on ? j + q : j];     // j < e, so keys[j] is safe
            const uint2 g = *reinterpret_cast<const uint2*>(
                h + (size_t)kv.x * D_OUT + li * 4);
            float vv = on ? __int_as_float(kv.y) : 0.f;
            acc.x += vv * bf16lo_f32(g.x);
            acc.y += vv * bf16hi_f32(g.x);
            acc.z += vv * bf16lo_f32(g.y);
            acc.w += vv * bf16hi_f32(g.y);
        }
        // combine the 4 edge slots (xor 16, then 32)
        acc.x += __shfl_xor(acc.x, 16, 64);
        acc.y += __shfl_xor(acc.y, 16, 64);
        acc.z += __shfl_xor(acc.z, 16, 64);
        acc.w += __shfl_xor(acc.w, 16, 64);
        acc.x += __shfl_xor(acc.x, 32, 64);
        acc.y += __shfl_xor(acc.y, 32, 64);
        acc.z += __shfl_xor(acc.z, 32, 64);
        acc.w += __shfl_xor(acc.w, 32, 64);

        if (q == 0) {
            float4 o;
            o.x = fmaxf(acc.x, 0.f);
            o.y = fmaxf(acc.y, 0.f);
            o.z = fmaxf(acc.z, 0.f);
            o.w = fmaxf(acc.w, 0.f);
            *reinterpret_cast<float4*>(out + (size_t)r * D_OUT + li * 4) = o;
        }
    }
}

// ---------------------------------------------------------------------------
extern "C" void kernel_launch(void* const* d_in, const int* in_sizes, int n_in,
                              void* d_out, int out_size, void* d_ws, size_t ws_size,
                              hipStream_t stream) {
    const float* A    = (const float*)d_in[0];
    const float* W    = (const float*)d_in[1];
    const float* vals = (const float*)d_in[2];
    const int*   rows = (const int*)d_in[3];
    const int*   cols = (const int*)d_in[4];
    float* out = (float*)d_out;

    const int N = out_size / D_OUT;                 // 100000
    const int E = in_sizes[2];                      // 1600000
    const int SB = (N + 1023) / 1024;               // 98

    // workspace layout (keys 8-aligned; h is bf16)
    char* ws = (char*)d_ws;
    unsigned short* h       = (unsigned short*)ws;                        // N*64 bf16
    int2*           keys    = (int2*)(ws + (size_t)N * D_OUT * 2);        // E int2
    unsigned short* wt      = (unsigned short*)((char*)keys + (size_t)E * 8);
    int*            counts  = (int*)((char*)wt + (size_t)D_OUT * K_DIM * 2); // N
    int*            scanned = counts + N;                                 // N+1
    int*            cursor  = scanned + N + 1;                            // N
    int*            bsum    = cursor + N;                                 // SB
    int*            bbase   = bsum + SB;                                  // SB

    wt_kernel<<<(D_OUT * K_DIM + 255) / 256, 256, 0, stream>>>(W, wt);
    gemm_kernel<<<(N + 63) / 64, 256, 0, stream>>>(A, wt, h, N);
    zero_kernel<<<(N + 255) / 256, 256, 0, stream>>>(counts, N);
    count_kernel<<<1024, 256, 0, stream>>>(rows, counts, E);
    scan1_kernel<<<SB, 256, 0, stream>>>(counts, bsum, N);
    scan2_kernel<<<1, 1024, 0, stream>>>(bsum, bbase, scanned, SB, N, E);
    scan3_kernel<<<SB, 256, 0, stream>>>(counts, bbase, scanned, cursor, N);
    partition_kernel<<<1024, 256, 0, stream>>>(rows, cols, vals, cursor, keys, E);
    agg_kernel<<<2048, 256, 0, stream>>>(h, keys, scanned, out, N);
}